// Round 6
// baseline (235.235 us; speedup 1.0000x reference)
//
#include <hip/hip_runtime.h>

#define T_TOK  16384
#define IN_F   1024
#define OUT_F  1024
#define NE     8
#define BM     64
#define BN     128
#define BK     32
#define NITER  (IN_F / BK)    // 32
#define NTHREADS 256
#define ROW_TILE_SLOTS (T_TOK / BM + NE)   // 264

typedef __bf16 bf16;
typedef bf16  bf16x4 __attribute__((ext_vector_type(4)));
typedef bf16  bf16x8 __attribute__((ext_vector_type(8)));
typedef float f32x4  __attribute__((ext_vector_type(4)));

#define NX_ELEM ((size_t)T_TOK * IN_F)          // 16,777,216
#define NW_ELEM ((size_t)NE * OUT_F * IN_F)     // 8,388,608
#define WS_NEED ((NX_ELEM + NW_ELEM) * sizeof(bf16))   // ~48 MB

// ---------------- Phase 1: fp32 -> bf16 conversion into workspace ----------
__global__ __launch_bounds__(NTHREADS)
void cvt_to_bf16(const float* __restrict__ x, const float* __restrict__ w,
                 bf16* __restrict__ xb, bf16* __restrict__ wb)
{
    const size_t NX8 = NX_ELEM / 8;
    const size_t NW8 = NW_ELEM / 8;
    size_t stride = (size_t)gridDim.x * blockDim.x;
    for (size_t i = (size_t)blockIdx.x * blockDim.x + threadIdx.x;
         i < NX8 + NW8; i += stride) {
        const float* src;
        bf16* dst;
        if (i < NX8) { src = x + i * 8;          dst = xb + i * 8; }
        else         { src = w + (i - NX8) * 8;  dst = wb + (i - NX8) * 8; }
        f32x4 v0 = *(const f32x4*)(src);
        f32x4 v1 = *(const f32x4*)(src + 4);
        bf16x8 h;
        #pragma unroll
        for (int j = 0; j < 4; ++j) { h[j] = (bf16)v0[j]; h[4 + j] = (bf16)v1[j]; }
        *(bf16x8*)dst = h;
    }
}

// ---------------- Phase 2: high-concurrency grouped GEMM -------------------
// 64x128 C tile (2112 blocks -> 33 waves/CU available), BK=32.
// A fragments: DIRECT from global bf16 (lane-private, no LDS), prefetched
// one iter ahead. B: double-buffered LDS via global_load_lds DMA with an
// XOR swizzle (q ^= (row>>1)&3) so frag ds_read_b128 is 2-way (free) instead
// of 8-way conflicted. One barrier per k-iter.
__global__ __launch_bounds__(NTHREADS)
void grouped_gemm_v6(const bf16* __restrict__ xb,
                     const bf16* __restrict__ wb,
                     const int*  __restrict__ seg_lens,
                     float* __restrict__ out)
{
    __shared__ __align__(16) bf16 Bs[2][BN * BK];

    const int m    = blockIdx.y;          // row-tile slot
    const int col0 = blockIdx.x * BN;     // output-feature tile

    // ---- slot m -> (expert, row0, rows); segments are contiguous ----
    int e_sel = -1, row0 = 0, rows = 0;
    {
        int start = 0, acct = 0;
        #pragma unroll
        for (int e = 0; e < NE; ++e) {
            int len = seg_lens[e];
            int nt  = (len + BM - 1) >> 6;
            if (e_sel < 0 && m >= acct && m < acct + nt) {
                e_sel = e;
                row0  = start + (m - acct) * BM;
                int rem = start + len - row0;
                rows = rem < BM ? rem : BM;
            }
            acct  += nt;
            start += len;
        }
    }
    if (e_sel < 0) return;   // surplus slot (block-uniform, before any barrier)

    const int tid  = threadIdx.x;
    const int lane = tid & 63;
    const int wave = tid >> 6;
    const int wm   = (wave >> 1) * 32;   // wave rows (32 of 64)
    const int wn   = (wave & 1) * 64;    // wave cols (64 of 128)
    const int quad = lane >> 4;
    const int l16  = lane & 15;

    // ---- A-fragment global pointers (k-invariant part) ----
    const bf16* agp[2];
    #pragma unroll
    for (int t = 0; t < 2; ++t) {
        int rg = row0 + wm + t * 16 + l16;
        if (rg > T_TOK - 1) rg = T_TOK - 1;   // clamp partial tile (masked at store)
        agp[t] = xb + (size_t)rg * IN_F + quad * 8;
    }

    // ---- B staging descriptors: chunk c=(t*256+tid) -> slot c in LDS,
    //      carrying global chunk (row=c>>2, q = (c&3) ^ ((row>>1)&3)) ----
    const bf16* bgp[2];
    int ldsoff[2];
    #pragma unroll
    for (int t = 0; t < 2; ++t) {
        int c    = t * NTHREADS + tid;
        int rowB = c >> 2;
        int q    = (c & 3) ^ ((rowB >> 1) & 3);
        bgp[t]    = wb + ((size_t)e_sel * OUT_F + col0 + rowB) * IN_F + q * 8;
        ldsoff[t] = c * 8;
    }

    // ---- B fragment LDS offsets (swizzle-aware), per col-tile u ----
    int boff[4];
    #pragma unroll
    for (int u = 0; u < 4; ++u) {
        int row = wn + u * 16 + l16;
        boff[u] = row * BK + ((quad ^ ((row >> 1) & 3)) * 8);
    }

    // ---- prologue: A frags for iter 0, B DMA into buf 0 ----
    bf16x8 apf[2];
    apf[0] = *(const bf16x8*)(agp[0]);
    apf[1] = *(const bf16x8*)(agp[1]);
    #pragma unroll
    for (int t = 0; t < 2; ++t)
        __builtin_amdgcn_global_load_lds(
            (const __attribute__((address_space(1))) void*)bgp[t],
            (__attribute__((address_space(3))) void*)(&Bs[0][ldsoff[t]]),
            16, 0, 0);

    f32x4 acc[2][4] = {};

    for (int i = 0; i < NITER; ++i) {
        __syncthreads();   // buf[i&1] DMA complete (all waves drained own vmcnt)
        const int cur = i & 1, nxt = cur ^ 1;
        const int kn  = ((i + 1) & (NITER - 1)) * BK;   // wraps last iter (harmless)

        // current A frags (loaded one iter ago — oldest outstanding loads)
        bf16x8 a0 = apf[0], a1 = apf[1];

        // prefetch A for i+1 FIRST, then B DMA for i+1 (vmcnt FIFO order:
        // next iter's wait on A drains nothing newer than these)
        apf[0] = *(const bf16x8*)(agp[0] + kn);
        apf[1] = *(const bf16x8*)(agp[1] + kn);
        #pragma unroll
        for (int t = 0; t < 2; ++t)
            __builtin_amdgcn_global_load_lds(
                (const __attribute__((address_space(1))) void*)(bgp[t] + kn),
                (__attribute__((address_space(3))) void*)(&Bs[nxt][ldsoff[t]]),
                16, 0, 0);

        // B fragments from swizzled LDS (2-way banked = free)
        bf16x8 bfr[4];
        #pragma unroll
        for (int u = 0; u < 4; ++u)
            bfr[u] = *(const bf16x8*)(&Bs[cur][boff[u]]);

        #pragma unroll
        for (int u = 0; u < 4; ++u) {
            acc[0][u] = __builtin_amdgcn_mfma_f32_16x16x32_bf16(a0, bfr[u], acc[0][u], 0, 0, 0);
            acc[1][u] = __builtin_amdgcn_mfma_f32_16x16x32_bf16(a1, bfr[u], acc[1][u], 0, 0, 0);
        }
    }

    // ---- epilogue: C/D layout col=lane&15, row=quad*4+reg (m89/m91) ----
    #pragma unroll
    for (int t = 0; t < 2; ++t) {
        #pragma unroll
        for (int r = 0; r < 4; ++r) {
            int row = wm + t * 16 + quad * 4 + r;
            if (row < rows) {
                size_t ob = (size_t)(row0 + row) * OUT_F + col0;
                #pragma unroll
                for (int u = 0; u < 4; ++u)
                    out[ob + wn + u * 16 + l16] = acc[t][u][r];
            }
        }
    }
}

// ---------------- Fallback: fused fp32 kernel (if ws too small) ------------
#define FBM 128
__global__ __launch_bounds__(NTHREADS)
void grouped_gemm_f32io_fused(const float* __restrict__ x,
                              const float* __restrict__ wgt,
                              const int*  __restrict__ seg_lens,
                              float* __restrict__ out)
{
    __shared__ __align__(16) bf16 As[FBM * BK];
    __shared__ __align__(16) bf16 Bsf[BN * BK];

    const int m    = blockIdx.y;
    const int col0 = blockIdx.x * BN;

    int e_sel = -1, row0 = 0, rows = 0;
    {
        int start = 0, acct = 0;
        #pragma unroll
        for (int e = 0; e < NE; ++e) {
            int len = seg_lens[e];
            int nt  = (len + FBM - 1) >> 7;
            if (e_sel < 0 && m >= acct && m < acct + nt) {
                e_sel = e;
                row0  = start + (m - acct) * FBM;
                int rem = start + len - row0;
                rows = rem < FBM ? rem : FBM;
            }
            acct  += nt;
            start += len;
        }
    }
    if (e_sel < 0) return;

    const int tid  = threadIdx.x;
    const int lane = tid & 63;
    const int wave = tid >> 6;
    const int wm   = (wave >> 1) * 64;
    const int wn   = (wave & 1) * 64;
    const int quad = lane >> 4;
    const int l16  = lane & 15;

    const float* wbase = wgt + ((size_t)e_sel * OUT_F + (size_t)col0) * IN_F;

    f32x4 acc[4][4] = {};

    for (int k0 = 0; k0 < IN_F; k0 += BK) {
        f32x4 a_st[4], b_st[4];
        #pragma unroll
        for (int t = 0; t < 4; ++t) {
            int c  = t * NTHREADS + tid;
            int rg = row0 + (c >> 3);
            if (rg > T_TOK - 1) rg = T_TOK - 1;
            a_st[t] = *(const f32x4*)(x + (size_t)rg * IN_F + k0 + (c & 7) * 4);
            b_st[t] = *(const f32x4*)(wbase + (size_t)(c >> 3) * IN_F + k0 + (c & 7) * 4);
        }
        __syncthreads();
        #pragma unroll
        for (int t = 0; t < 4; ++t) {
            int c = t * NTHREADS + tid;
            bf16x4 ha, hb;
            #pragma unroll
            for (int j = 0; j < 4; ++j) { ha[j] = (bf16)a_st[t][j]; hb[j] = (bf16)b_st[t][j]; }
            *(bf16x4*)(&As[(c >> 3) * BK + (c & 7) * 4]) = ha;
            *(bf16x4*)(&Bsf[(c >> 3) * BK + (c & 7) * 4]) = hb;
        }
        __syncthreads();

        bf16x8 af[4], bfr[4];
        #pragma unroll
        for (int t = 0; t < 4; ++t)
            af[t] = *(const bf16x8*)(&As[(wm + t * 16 + l16) * BK + quad * 8]);
        #pragma unroll
        for (int u = 0; u < 4; ++u)
            bfr[u] = *(const bf16x8*)(&Bsf[(wn + u * 16 + l16) * BK + quad * 8]);

        #pragma unroll
        for (int t = 0; t < 4; ++t)
            #pragma unroll
            for (int u = 0; u < 4; ++u)
                acc[t][u] = __builtin_amdgcn_mfma_f32_16x16x32_bf16(
                    af[t], bfr[u], acc[t][u], 0, 0, 0);
    }

    #pragma unroll
    for (int t = 0; t < 4; ++t) {
        #pragma unroll
        for (int r = 0; r < 4; ++r) {
            int row = wm + t * 16 + quad * 4 + r;
            if (row < rows) {
                size_t ob = (size_t)(row0 + row) * OUT_F + col0;
                #pragma unroll
                for (int u = 0; u < 4; ++u)
                    out[ob + wn + u * 16 + l16] = acc[t][u][r];
            }
        }
    }
}

extern "C" void kernel_launch(void* const* d_in, const int* in_sizes, int n_in,
                              void* d_out, int out_size, void* d_ws, size_t ws_size,
                              hipStream_t stream) {
    const float* x   = (const float*)d_in[0];
    const float* wgt = (const float*)d_in[1];
    const int*   seg = (const int*)d_in[2];
    float* out = (float*)d_out;

    dim3 block(NTHREADS, 1, 1);

    if (ws_size >= WS_NEED) {
        bf16* xb = (bf16*)d_ws;
        bf16* wb = xb + NX_ELEM;
        cvt_to_bf16<<<3072, block, 0, stream>>>(x, wgt, xb, wb);
        dim3 grid2(OUT_F / BN, ROW_TILE_SLOTS, 1);
        grouped_gemm_v6<<<grid2, block, 0, stream>>>(xb, wb, seg, out);
    } else {
        dim3 gridf(OUT_F / BN, T_TOK / FBM + NE, 1);
        grouped_gemm_f32io_fused<<<gridf, block, 0, stream>>>(x, wgt, seg, out);
    }
}